// Round 8
// baseline (73.618 us; speedup 1.0000x reference)
//
#include <hip/hip_runtime.h>

#define NB 128
#define NS 65536

// ---- VALU-pipe cross-lane helpers -----------------------------------------
template <int CTRL>
__device__ __forceinline__ float dppqp(float x) {
  return __int_as_float(__builtin_amdgcn_update_dpp(
      0, __float_as_int(x), CTRL, 0xF, 0xF, false));
}
template <int OFF>
__device__ __forceinline__ float dswz(float x) {
  return __int_as_float(__builtin_amdgcn_ds_swizzle(__float_as_int(x), OFF));
}

// In-wave 256-point Walsh-Hadamard transform (unnormalized).
// Element e = 4*lane + q. Bits 0,1 in registers; lane bits:
//  xor1,xor2 via DPP quad_perm; xor4,xor8 via ds_swizzle;
//  xor16,xor32 via v_permlane16/32_swap (VALU).
__device__ __forceinline__ void wht256(float (&xr)[4], float (&xi)[4], int lane) {
  {
    float t;
    t = xr[0]; xr[0] = t + xr[1]; xr[1] = t - xr[1];
    t = xr[2]; xr[2] = t + xr[3]; xr[3] = t - xr[3];
    t = xi[0]; xi[0] = t + xi[1]; xi[1] = t - xi[1];
    t = xi[2]; xi[2] = t + xi[3]; xi[3] = t - xi[3];
    t = xr[0]; xr[0] = t + xr[2]; xr[2] = t - xr[2];
    t = xr[1]; xr[1] = t + xr[3]; xr[3] = t - xr[3];
    t = xi[0]; xi[0] = t + xi[2]; xi[2] = t - xi[2];
    t = xi[1]; xi[1] = t + xi[3]; xi[3] = t - xi[3];
  }
  const float s1  = (lane & 1)  ? -1.f : 1.f;
  const float s2  = (lane & 2)  ? -1.f : 1.f;
  const float s4  = (lane & 4)  ? -1.f : 1.f;
  const float s8  = (lane & 8)  ? -1.f : 1.f;
  const float s16 = (lane & 16) ? -1.f : 1.f;
  const float s32 = (lane & 32) ? -1.f : 1.f;
#pragma unroll
  for (int q = 0; q < 4; ++q) {
    xr[q] = fmaf(s1, xr[q], dppqp<0xB1>(xr[q]));
    xi[q] = fmaf(s1, xi[q], dppqp<0xB1>(xi[q]));
  }
#pragma unroll
  for (int q = 0; q < 4; ++q) {
    xr[q] = fmaf(s2, xr[q], dppqp<0x4E>(xr[q]));
    xi[q] = fmaf(s2, xi[q], dppqp<0x4E>(xi[q]));
  }
#pragma unroll
  for (int q = 0; q < 4; ++q) {
    xr[q] = fmaf(s4, xr[q], dswz<0x101F>(xr[q]));
    xi[q] = fmaf(s4, xi[q], dswz<0x101F>(xi[q]));
  }
#pragma unroll
  for (int q = 0; q < 4; ++q) {
    xr[q] = fmaf(s8, xr[q], dswz<0x201F>(xr[q]));
    xi[q] = fmaf(s8, xi[q], dswz<0x201F>(xi[q]));
  }
#pragma unroll
  for (int q = 0; q < 4; ++q) {
    {
      auto r = __builtin_amdgcn_permlane16_swap(__float_as_uint(xr[q]),
                                                __float_as_uint(xr[q]), false, false);
      xr[q] = fmaf(s16, __uint_as_float(r[1]), __uint_as_float(r[0]));
    }
    {
      auto r = __builtin_amdgcn_permlane16_swap(__float_as_uint(xi[q]),
                                                __float_as_uint(xi[q]), false, false);
      xi[q] = fmaf(s16, __uint_as_float(r[1]), __uint_as_float(r[0]));
    }
  }
#pragma unroll
  for (int q = 0; q < 4; ++q) {
    {
      auto r = __builtin_amdgcn_permlane32_swap(__float_as_uint(xr[q]),
                                                __float_as_uint(xr[q]), false, false);
      xr[q] = fmaf(s32, __uint_as_float(r[1]), __uint_as_float(r[0]));
    }
    {
      auto r = __builtin_amdgcn_permlane32_swap(__float_as_uint(xi[q]),
                                                __float_as_uint(xi[q]), false, false);
      xi[q] = fmaf(s32, __uint_as_float(r[1]), __uint_as_float(r[0]));
    }
  }
}

// K1: A_hi = WHT·diag(ph_hi)·WHT along the hi axis. Reads natural [b][hi][lo]
// in [256 hi x 16 lo] tiles (LDS transpose in/out), writes complex-interleaved
// T[b][m_hi][lo] in full 128B lines; norm^2 partials.
// 256 threads, 4 rows/wave (64 independent WHT chains per CU for latency
// hiding). lo-tile pairing keeps sibling tiles on the same XCD.
__global__ __launch_bounds__(256, 4) void k1_ahi(const float* __restrict__ sre,
                                                 const float* __restrict__ sim,
                                                 const float* __restrict__ thetas,
                                                 float* __restrict__ T,
                                                 float* __restrict__ partial) {
  __shared__ float sr[16][260];
  __shared__ float si[16][260];
  __shared__ float2 phh4[64];
  __shared__ float2 phHQ[4];
  __shared__ float th[16];
  __shared__ float red[4];
  const int bid = blockIdx.x;
  const int b = bid >> 4, s = bid & 15;
  const int tl = ((s & 7) << 1) | (s >> 3);  // pair tiles 2u,2u+1 on same XCD
  const int lo0 = tl * 16;
  const int tid = threadIdx.x, lane = tid & 63, w = tid >> 6;
  if (tid < 16) th[tid] = thetas[b * 16 + tid];
  __syncthreads();
  if (tid < 64) {
    // phase tables over hi index h = (l<<2)|q; ang(h)=sum th[7-bit] per set bit
    float a = 0.f;
#pragma unroll
    for (int i = 0; i < 6; ++i)
      if ((tid >> (5 - i)) & 1) a += th[i];
    phh4[tid] = make_float2(cosf(0.5f * a), -sinf(0.5f * a));
    if (tid < 4) {
      float aq = 0.f;
      if (tid & 1) aq += th[7];
      if (tid & 2) aq += th[6];
      phHQ[tid] = make_float2(cosf(0.5f * aq), -sinf(0.5f * aq));
    }
  }
  // load phase: transpose [hi][lo-chunk] -> LDS [lo_local][hi]
  const float* pre = sre + ((size_t)b << 16);
  const float* pim = sim + ((size_t)b << 16);
  float acc = 0.f;
  const int c = tid & 3, jh0 = tid >> 2;
#pragma unroll
  for (int r2 = 0; r2 < 4; ++r2) {
    const int j = jh0 + r2 * 64;
    const float4 vr = *reinterpret_cast<const float4*>(pre + j * 256 + lo0 + c * 4);
    const float4 vi = *reinterpret_cast<const float4*>(pim + j * 256 + lo0 + c * 4);
    acc += vr.x*vr.x + vr.y*vr.y + vr.z*vr.z + vr.w*vr.w
         + vi.x*vi.x + vi.y*vi.y + vi.z*vi.z + vi.w*vi.w;
    sr[c*4+0][j] = vr.x; sr[c*4+1][j] = vr.y; sr[c*4+2][j] = vr.z; sr[c*4+3][j] = vr.w;
    si[c*4+0][j] = vi.x; si[c*4+1][j] = vi.y; si[c*4+2][j] = vi.z; si[c*4+3][j] = vi.w;
  }
#pragma unroll
  for (int m = 32; m >= 1; m >>= 1) acc += __shfl_xor(acc, m, 64);
  if (lane == 0) red[w] = acc;
  __syncthreads();
  if (tid == 0) partial[bid] = red[0] + red[1] + red[2] + red[3];
  // compute phase: each wave owns 4 rows (independent chains for ILP)
#pragma unroll
  for (int r = 0; r < 4; ++r) {
    const int ll = w * 4 + r;
    const float4 a4 = *reinterpret_cast<const float4*>(&sr[ll][lane * 4]);
    const float4 b4 = *reinterpret_cast<const float4*>(&si[ll][lane * 4]);
    float xr[4] = {a4.x, a4.y, a4.z, a4.w};
    float xi[4] = {b4.x, b4.y, b4.z, b4.w};
    wht256(xr, xi, lane);
    const float2 p4 = phh4[lane];
#pragma unroll
    for (int q = 0; q < 4; ++q) {
      const float2 pq = phHQ[q];
      const float pr = p4.x * pq.x - p4.y * pq.y;
      const float pi = p4.x * pq.y + p4.y * pq.x;
      const float ur = xr[q], ui = xi[q];
      xr[q] = ur * pr - ui * pi;
      xi[q] = ur * pi + ui * pr;
    }
    wht256(xr, xi, lane);
    *reinterpret_cast<float4*>(&sr[ll][lane * 4]) = make_float4(xr[0], xr[1], xr[2], xr[3]);
    *reinterpret_cast<float4*>(&si[ll][lane * 4]) = make_float4(xi[0], xi[1], xi[2], xi[3]);
  }
  __syncthreads();
  // store phase: T[b][m_hi][lo] complex interleaved; 2 threads per m_hi row,
  // two row-iterations (128B line filled by 8 stores from adjacent lanes)
  float* Tb = T + ((size_t)b << 17);
  const int mrow = tid >> 1, L = (tid & 1) * 8;
#pragma unroll
  for (int it = 0; it < 2; ++it) {
    const int m = mrow + it * 128;
    float* dst = Tb + ((size_t)m << 9) + (size_t)(lo0 + L) * 2;
#pragma unroll
    for (int j = 0; j < 4; ++j) {
      const int l0 = L + 2 * j;
      *reinterpret_cast<float4*>(dst + j * 4) =
          make_float4(sr[l0][m], si[l0][m], sr[l0 + 1][m], si[l0 + 1][m]);
    }
  }
}

// K2: A_lo = WHT·diag(ph_lo)·WHT along contiguous lo axis, |.|^2 * iv,
// permuted scatter out[srow[m_hi] ^ sloL[lane] ^ sloQ[q]] (lo-varying = the
// empirically fast orientation). GF(2)/phase linearity factors all tables to
// one conflict-free LDS read per lane. XCD swizzle: each XCD owns 16 batches.
__global__ __launch_bounds__(256, 8) void k2_alo_scatter(const float* __restrict__ T,
                                                         const float* __restrict__ thetas,
                                                         const int* __restrict__ cnot,
                                                         const float* __restrict__ partial,
                                                         float* __restrict__ outp) {
  __shared__ float2 phl4[64];
  __shared__ float2 phLQ[4];
  __shared__ int sloL[64];
  __shared__ int tj[16];
  __shared__ int srow16[16];
  __shared__ float th[16];
  __shared__ float shinv;
  const int bid = blockIdx.x;
  const int x = bid & 7, s2 = bid >> 3;
  const int b = x * 16 + (s2 >> 4), tile = s2 & 15;
  const int tid = threadIdx.x, lane = tid & 63, w = tid >> 6;
  if (tid < 16) {
    th[tid] = thetas[b * 16 + tid];
    int v = 0;
#pragma unroll
    for (int i = 0; i < 16; ++i) v |= ((cnot[1 << i] >> tid) & 1) << i;
    tj[tid] = v;
  }
  if (tid == 0) {
    float sum = 0.f;
#pragma unroll
    for (int k = 0; k < 16; ++k) sum += partial[b * 16 + k];
    shinv = 1.0f / (sum * 4294967296.0f);  // fold 2^-32 WHT scaling + 1/norm^2
  }
  __syncthreads();
  if (tid < 64) {
    float a = 0.f;
#pragma unroll
    for (int i = 0; i < 6; ++i)
      if ((tid >> (5 - i)) & 1) a += th[8 + i];
    phl4[tid] = make_float2(cosf(0.5f * a), -sinf(0.5f * a));
    int v = 0;
#pragma unroll
    for (int bb = 0; bb < 6; ++bb)
      if ((tid >> bb) & 1) v ^= tj[2 + bb];
    sloL[tid] = v;
    if (tid < 4) {
      float aq = 0.f;
      if (tid & 1) aq += th[15];
      if (tid & 2) aq += th[14];
      phLQ[tid] = make_float2(cosf(0.5f * aq), -sinf(0.5f * aq));
    }
  }
  if (tid < 16) {
    const int mh = tile * 16 + tid;
    int v = 0;
#pragma unroll
    for (int bb = 0; bb < 8; ++bb)
      if ((mh >> bb) & 1) v ^= tj[8 + bb];
    srow16[tid] = v;
  }
  __syncthreads();
  const float* Tb = T + ((size_t)b << 17);
  float* ob = outp + ((size_t)b << 16);
  const float iv = shinv;
  const float2 p4 = phl4[lane];
  const int sL = sloL[lane];
  const int sq1 = tj[0], sq2 = tj[1], sq3 = tj[0] ^ tj[1];
  float2 p4q[4];
#pragma unroll
  for (int q = 0; q < 4; ++q) {
    const float2 pq = phLQ[q];
    p4q[q].x = p4.x * pq.x - p4.y * pq.y;
    p4q[q].y = p4.x * pq.y + p4.y * pq.x;
  }
#pragma unroll
  for (int r = 0; r < 4; ++r) {
    const int rl = w * 4 + r;
    const int mh = tile * 16 + rl;
    const float4 va = *reinterpret_cast<const float4*>(Tb + ((size_t)mh << 9) + lane * 8);
    const float4 vb = *reinterpret_cast<const float4*>(Tb + ((size_t)mh << 9) + lane * 8 + 4);
    float xr[4] = {va.x, va.z, vb.x, vb.z};
    float xi[4] = {va.y, va.w, vb.y, vb.w};
    wht256(xr, xi, lane);
#pragma unroll
    for (int q = 0; q < 4; ++q) {
      const float ur = xr[q], ui = xi[q];
      xr[q] = ur * p4q[q].x - ui * p4q[q].y;
      xi[q] = ur * p4q[q].y + ui * p4q[q].x;
    }
    wht256(xr, xi, lane);
    const int base = srow16[rl] ^ sL;
    ob[base]       = (xr[0] * xr[0] + xi[0] * xi[0]) * iv;
    ob[base ^ sq1] = (xr[1] * xr[1] + xi[1] * xi[1]) * iv;
    ob[base ^ sq2] = (xr[2] * xr[2] + xi[2] * xi[2]) * iv;
    ob[base ^ sq3] = (xr[3] * xr[3] + xi[3] * xi[3]) * iv;
  }
}

extern "C" void kernel_launch(void* const* d_in, const int* in_sizes, int n_in,
                              void* d_out, int out_size, void* d_ws, size_t ws_size,
                              hipStream_t stream) {
  const float* sre = (const float*)d_in[0];
  const float* sim = (const float*)d_in[1];
  const float* thetas = (const float*)d_in[2];
  const int* cnot = (const int*)d_in[3];
  float* outp = (float*)d_out;
  char* w = (char*)d_ws;
  const size_t CPLANE = (size_t)NB * NS * 2 * sizeof(float);  // 64 MB complex
  if (ws_size < CPLANE + 8192) return;  // need 64 MB scratch + partials
  float* T = (float*)(w);
  float* partial = (float*)(w + CPLANE);  // 2048 floats

  hipLaunchKernelGGL(k1_ahi, dim3(2048), dim3(256), 0, stream, sre, sim, thetas, T, partial);
  hipLaunchKernelGGL(k2_alo_scatter, dim3(2048), dim3(256), 0, stream, T, thetas, cnot, partial, outp);
}

// Round 9
// 62.187 us; speedup vs baseline: 1.1838x; 1.1838x over previous
//
#include <hip/hip_runtime.h>

#define NB 128
#define NS 65536

// ---- VALU-pipe cross-lane helpers -----------------------------------------
template <int CTRL>
__device__ __forceinline__ float dppqp(float x) {
  return __int_as_float(__builtin_amdgcn_update_dpp(
      0, __float_as_int(x), CTRL, 0xF, 0xF, false));
}
template <int OFF>
__device__ __forceinline__ float dswz(float x) {
  return __int_as_float(__builtin_amdgcn_ds_swizzle(__float_as_int(x), OFF));
}

// In-wave 256-point Walsh-Hadamard transform (unnormalized).
// Element e = 4*lane + q. Bits 0,1 in registers; lane bits:
//  xor1,xor2 via DPP quad_perm; xor4,xor8 via ds_swizzle;
//  xor16,xor32 via v_permlane16/32_swap (VALU).
__device__ __forceinline__ void wht256(float (&xr)[4], float (&xi)[4], int lane) {
  {
    float t;
    t = xr[0]; xr[0] = t + xr[1]; xr[1] = t - xr[1];
    t = xr[2]; xr[2] = t + xr[3]; xr[3] = t - xr[3];
    t = xi[0]; xi[0] = t + xi[1]; xi[1] = t - xi[1];
    t = xi[2]; xi[2] = t + xi[3]; xi[3] = t - xi[3];
    t = xr[0]; xr[0] = t + xr[2]; xr[2] = t - xr[2];
    t = xr[1]; xr[1] = t + xr[3]; xr[3] = t - xr[3];
    t = xi[0]; xi[0] = t + xi[2]; xi[2] = t - xi[2];
    t = xi[1]; xi[1] = t + xi[3]; xi[3] = t - xi[3];
  }
  const float s1  = (lane & 1)  ? -1.f : 1.f;
  const float s2  = (lane & 2)  ? -1.f : 1.f;
  const float s4  = (lane & 4)  ? -1.f : 1.f;
  const float s8  = (lane & 8)  ? -1.f : 1.f;
  const float s16 = (lane & 16) ? -1.f : 1.f;
  const float s32 = (lane & 32) ? -1.f : 1.f;
#pragma unroll
  for (int q = 0; q < 4; ++q) {
    xr[q] = fmaf(s1, xr[q], dppqp<0xB1>(xr[q]));
    xi[q] = fmaf(s1, xi[q], dppqp<0xB1>(xi[q]));
  }
#pragma unroll
  for (int q = 0; q < 4; ++q) {
    xr[q] = fmaf(s2, xr[q], dppqp<0x4E>(xr[q]));
    xi[q] = fmaf(s2, xi[q], dppqp<0x4E>(xi[q]));
  }
#pragma unroll
  for (int q = 0; q < 4; ++q) {
    xr[q] = fmaf(s4, xr[q], dswz<0x101F>(xr[q]));
    xi[q] = fmaf(s4, xi[q], dswz<0x101F>(xi[q]));
  }
#pragma unroll
  for (int q = 0; q < 4; ++q) {
    xr[q] = fmaf(s8, xr[q], dswz<0x201F>(xr[q]));
    xi[q] = fmaf(s8, xi[q], dswz<0x201F>(xi[q]));
  }
#pragma unroll
  for (int q = 0; q < 4; ++q) {
    {
      auto r = __builtin_amdgcn_permlane16_swap(__float_as_uint(xr[q]),
                                                __float_as_uint(xr[q]), false, false);
      xr[q] = fmaf(s16, __uint_as_float(r[1]), __uint_as_float(r[0]));
    }
    {
      auto r = __builtin_amdgcn_permlane16_swap(__float_as_uint(xi[q]),
                                                __float_as_uint(xi[q]), false, false);
      xi[q] = fmaf(s16, __uint_as_float(r[1]), __uint_as_float(r[0]));
    }
  }
#pragma unroll
  for (int q = 0; q < 4; ++q) {
    {
      auto r = __builtin_amdgcn_permlane32_swap(__float_as_uint(xr[q]),
                                                __float_as_uint(xr[q]), false, false);
      xr[q] = fmaf(s32, __uint_as_float(r[1]), __uint_as_float(r[0]));
    }
    {
      auto r = __builtin_amdgcn_permlane32_swap(__float_as_uint(xi[q]),
                                                __float_as_uint(xi[q]), false, false);
      xi[q] = fmaf(s32, __uint_as_float(r[1]), __uint_as_float(r[0]));
    }
  }
}

// K1: A_hi = WHT·diag(ph_hi)·WHT along the hi axis. 32-lo x 256-hi tile,
// 1024 threads (16 waves x 2 rows). Global reads are exact 128B lines per
// hi-row; LDS transpose in/out; T[b][m_hi][lo] written complex-interleaved
// in 64B-contiguous chunks. 66.5KB LDS -> 2 blocks/CU = 32 waves/CU nominal.
__global__ __launch_bounds__(1024, 8) void k1_ahi(const float* __restrict__ sre,
                                                  const float* __restrict__ sim,
                                                  const float* __restrict__ thetas,
                                                  float* __restrict__ T,
                                                  float* __restrict__ partial) {
  __shared__ float sr[32][260];
  __shared__ float si[32][260];
  __shared__ float2 phh4[64];
  __shared__ float2 phHQ[4];
  __shared__ float th[16];
  __shared__ float red[16];
  const int bid = blockIdx.x;
  const int b = bid >> 3, tile = bid & 7;  // tile == XCD slot
  const int lo0 = tile * 32;
  const int tid = threadIdx.x, lane = tid & 63, w = tid >> 6;
  if (tid < 16) th[tid] = thetas[b * 16 + tid];
  __syncthreads();
  if (tid < 64) {
    // phase tables over hi index h = (l<<2)|q; ang_hi(h) = sum th[7-t] over set bits t
    float a = 0.f;
#pragma unroll
    for (int i = 0; i < 6; ++i)
      if ((tid >> (5 - i)) & 1) a += th[i];
    phh4[tid] = make_float2(cosf(0.5f * a), -sinf(0.5f * a));
    if (tid < 4) {
      float aq = 0.f;
      if (tid & 1) aq += th[7];
      if (tid & 2) aq += th[6];
      phHQ[tid] = make_float2(cosf(0.5f * aq), -sinf(0.5f * aq));
    }
  }
  // load phase: full 128B line per hi-row j -> LDS transpose [lo_local][j]
  const float* pre = sre + ((size_t)b << 16);
  const float* pim = sim + ((size_t)b << 16);
  float acc = 0.f;
  const int c = tid & 7, jr = tid >> 3;
#pragma unroll
  for (int it = 0; it < 2; ++it) {
    const int j = jr + it * 128;
    const float4 vr = *reinterpret_cast<const float4*>(pre + j * 256 + lo0 + c * 4);
    const float4 vi = *reinterpret_cast<const float4*>(pim + j * 256 + lo0 + c * 4);
    acc += vr.x*vr.x + vr.y*vr.y + vr.z*vr.z + vr.w*vr.w
         + vi.x*vi.x + vi.y*vi.y + vi.z*vi.z + vi.w*vi.w;
    sr[c*4+0][j] = vr.x; sr[c*4+1][j] = vr.y; sr[c*4+2][j] = vr.z; sr[c*4+3][j] = vr.w;
    si[c*4+0][j] = vi.x; si[c*4+1][j] = vi.y; si[c*4+2][j] = vi.z; si[c*4+3][j] = vi.w;
  }
#pragma unroll
  for (int m = 32; m >= 1; m >>= 1) acc += __shfl_xor(acc, m, 64);
  if (lane == 0) red[w] = acc;
  __syncthreads();
  if (tid == 0) {
    float sm = 0.f;
#pragma unroll
    for (int k = 0; k < 16; ++k) sm += red[k];
    partial[bid] = sm;
  }
  // compute phase: wave w owns rows 2w, 2w+1 (hi contiguous in LDS rows)
#pragma unroll
  for (int r = 0; r < 2; ++r) {
    const int ll = w * 2 + r;
    const float4 a4 = *reinterpret_cast<const float4*>(&sr[ll][lane * 4]);
    const float4 b4 = *reinterpret_cast<const float4*>(&si[ll][lane * 4]);
    float xr[4] = {a4.x, a4.y, a4.z, a4.w};
    float xi[4] = {b4.x, b4.y, b4.z, b4.w};
    wht256(xr, xi, lane);
    const float2 p4 = phh4[lane];
#pragma unroll
    for (int q = 0; q < 4; ++q) {
      const float2 pq = phHQ[q];
      const float pr = p4.x * pq.x - p4.y * pq.y;
      const float pi = p4.x * pq.y + p4.y * pq.x;
      const float ur = xr[q], ui = xi[q];
      xr[q] = ur * pr - ui * pi;
      xi[q] = ur * pi + ui * pr;
    }
    wht256(xr, xi, lane);
    *reinterpret_cast<float4*>(&sr[ll][lane * 4]) = make_float4(xr[0], xr[1], xr[2], xr[3]);
    *reinterpret_cast<float4*>(&si[ll][lane * 4]) = make_float4(xi[0], xi[1], xi[2], xi[3]);
  }
  __syncthreads();
  // store phase: T[b][m_hi][lo] complex interleaved; 4 threads per m_hi row,
  // each instruction writes 64B contiguous (4 lanes x float4)
  float* Tb = T + ((size_t)b << 17);
  const int m = tid >> 2, sub = tid & 3;
  float* dst = Tb + ((size_t)m << 9) + (size_t)lo0 * 2;
#pragma unroll
  for (int j = 0; j < 4; ++j) {
    const int l0 = 8 * j + 2 * sub;
    *reinterpret_cast<float4*>(dst + l0 * 2) =
        make_float4(sr[l0][m], si[l0][m], sr[l0 + 1][m], si[l0 + 1][m]);
  }
}

// K2: A_lo = WHT·diag(ph_lo)·WHT along contiguous lo axis, |.|^2 * iv,
// permuted scatter out[srow[m_hi] ^ sloL[lane] ^ sloQ[q]] (lo-varying = the
// empirically fast orientation). GF(2)/phase linearity factors all tables to
// one conflict-free LDS read per lane. XCD swizzle: each XCD owns 16 batches.
__global__ __launch_bounds__(256, 8) void k2_alo_scatter(const float* __restrict__ T,
                                                         const float* __restrict__ thetas,
                                                         const int* __restrict__ cnot,
                                                         const float* __restrict__ partial,
                                                         float* __restrict__ outp) {
  __shared__ float2 phl4[64];
  __shared__ float2 phLQ[4];
  __shared__ int sloL[64];
  __shared__ int tj[16];
  __shared__ int srow16[16];
  __shared__ float th[16];
  __shared__ float shinv;
  const int bid = blockIdx.x;
  const int x = bid & 7, s2 = bid >> 3;
  const int b = x * 16 + (s2 >> 4), tile = s2 & 15;
  const int tid = threadIdx.x, lane = tid & 63, w = tid >> 6;
  if (tid < 16) {
    th[tid] = thetas[b * 16 + tid];
    int v = 0;
#pragma unroll
    for (int i = 0; i < 16; ++i) v |= ((cnot[1 << i] >> tid) & 1) << i;
    tj[tid] = v;
  }
  if (tid == 0) {
    float sum = 0.f;
#pragma unroll
    for (int k = 0; k < 8; ++k) sum += partial[b * 8 + k];
    shinv = 1.0f / (sum * 4294967296.0f);  // fold 2^-32 WHT scaling + 1/norm^2
  }
  __syncthreads();
  if (tid < 64) {
    float a = 0.f;
#pragma unroll
    for (int i = 0; i < 6; ++i)
      if ((tid >> (5 - i)) & 1) a += th[8 + i];
    phl4[tid] = make_float2(cosf(0.5f * a), -sinf(0.5f * a));
    int v = 0;
#pragma unroll
    for (int bb = 0; bb < 6; ++bb)
      if ((tid >> bb) & 1) v ^= tj[2 + bb];
    sloL[tid] = v;
    if (tid < 4) {
      float aq = 0.f;
      if (tid & 1) aq += th[15];
      if (tid & 2) aq += th[14];
      phLQ[tid] = make_float2(cosf(0.5f * aq), -sinf(0.5f * aq));
    }
  }
  if (tid < 16) {
    const int mh = tile * 16 + tid;
    int v = 0;
#pragma unroll
    for (int bb = 0; bb < 8; ++bb)
      if ((mh >> bb) & 1) v ^= tj[8 + bb];
    srow16[tid] = v;
  }
  __syncthreads();
  const float* Tb = T + ((size_t)b << 17);
  float* ob = outp + ((size_t)b << 16);
  const float iv = shinv;
  const float2 p4 = phl4[lane];
  const int sL = sloL[lane];
  const int sq1 = tj[0], sq2 = tj[1], sq3 = tj[0] ^ tj[1];
  float2 p4q[4];
#pragma unroll
  for (int q = 0; q < 4; ++q) {
    const float2 pq = phLQ[q];
    p4q[q].x = p4.x * pq.x - p4.y * pq.y;
    p4q[q].y = p4.x * pq.y + p4.y * pq.x;
  }
#pragma unroll
  for (int r = 0; r < 4; ++r) {
    const int rl = w * 4 + r;
    const int mh = tile * 16 + rl;
    const float4 va = *reinterpret_cast<const float4*>(Tb + ((size_t)mh << 9) + lane * 8);
    const float4 vb = *reinterpret_cast<const float4*>(Tb + ((size_t)mh << 9) + lane * 8 + 4);
    float xr[4] = {va.x, va.z, vb.x, vb.z};
    float xi[4] = {va.y, va.w, vb.y, vb.w};
    wht256(xr, xi, lane);
#pragma unroll
    for (int q = 0; q < 4; ++q) {
      const float ur = xr[q], ui = xi[q];
      xr[q] = ur * p4q[q].x - ui * p4q[q].y;
      xi[q] = ur * p4q[q].y + ui * p4q[q].x;
    }
    wht256(xr, xi, lane);
    const int base = srow16[rl] ^ sL;
    ob[base]       = (xr[0] * xr[0] + xi[0] * xi[0]) * iv;
    ob[base ^ sq1] = (xr[1] * xr[1] + xi[1] * xi[1]) * iv;
    ob[base ^ sq2] = (xr[2] * xr[2] + xi[2] * xi[2]) * iv;
    ob[base ^ sq3] = (xr[3] * xr[3] + xi[3] * xi[3]) * iv;
  }
}

extern "C" void kernel_launch(void* const* d_in, const int* in_sizes, int n_in,
                              void* d_out, int out_size, void* d_ws, size_t ws_size,
                              hipStream_t stream) {
  const float* sre = (const float*)d_in[0];
  const float* sim = (const float*)d_in[1];
  const float* thetas = (const float*)d_in[2];
  const int* cnot = (const int*)d_in[3];
  float* outp = (float*)d_out;
  char* w = (char*)d_ws;
  const size_t CPLANE = (size_t)NB * NS * 2 * sizeof(float);  // 64 MB complex
  if (ws_size < CPLANE + 8192) return;  // need 64 MB scratch + partials
  float* T = (float*)(w);
  float* partial = (float*)(w + CPLANE);  // 1024 floats

  hipLaunchKernelGGL(k1_ahi, dim3(1024), dim3(1024), 0, stream, sre, sim, thetas, T, partial);
  hipLaunchKernelGGL(k2_alo_scatter, dim3(2048), dim3(256), 0, stream, T, thetas, cnot, partial, outp);
}